// Round 14
// baseline (21.863 us; speedup 1.0000x reference)
//
#include <hip/hip_runtime.h>
#include <hip/hip_bf16.h>

#define EDIM  128
#define QN    32
#define DN    256
#define NK    11

typedef __attribute__((ext_vector_type(8))) short bf16x8;
typedef __attribute__((ext_vector_type(4))) float f32x4;

#define EXP2F(x) __builtin_amdgcn_exp2f(x)

// ---- DPP 16-lane sum (within each aligned group of 16 lanes) ----
template <int CTRL>
static __device__ inline float dpp_add(float x) {
    int y = __builtin_amdgcn_update_dpp(0, __float_as_int(x), CTRL, 0xF, 0xF, true);
    return x + __int_as_float(y);
}
static __device__ inline float sum16(float x) {
    x = dpp_add<0xB1>(x);    // quad_perm xor 1
    x = dpp_add<0x4E>(x);    // quad_perm xor 2
    x = dpp_add<0x124>(x);   // row_ror:4
    x = dpp_add<0x128>(x);   // row_ror:8
    return x;
}

// XOR row swizzle within a 256B bf16 row
static __device__ inline int swz(int r, int c) { return c ^ ((r & 7) << 4); }

static __device__ inline bf16x8 pack8(float4 a, float4 b) {
    union { bf16x8 v; __hip_bfloat16 h[8]; } u;
    u.h[0] = __float2bfloat16(a.x); u.h[1] = __float2bfloat16(a.y);
    u.h[2] = __float2bfloat16(a.z); u.h[3] = __float2bfloat16(a.w);
    u.h[4] = __float2bfloat16(b.x); u.h[5] = __float2bfloat16(b.y);
    u.h[6] = __float2bfloat16(b.z); u.h[7] = __float2bfloat16(b.w);
    return u.v;
}
static __device__ inline float sumsq8(float4 a, float4 b) {
    float s = a.x * a.x + a.y * a.y + a.z * a.z + a.w * a.w;
    s = fmaf(b.x, b.x, s); s = fmaf(b.y, b.y, s);
    s = fmaf(b.z, b.z, s); s = fmaf(b.w, b.w, s);
    return s;
}

// ---------------- fused kernel: one 8-wave block per batch ----------------
// All global loads (tokens + rows) issued up front; rows PRE-NORMALIZED into
// swizzled bf16 LDS; tm = raw MFMA accumulator; SCALAR Gaussian chain (R12).
__global__ __launch_bounds__(512, 4) void knrm_fused(const int* __restrict__ qtok,
                                                     const int* __restrict__ dtok,
                                                     const float* __restrict__ emb,
                                                     const float* __restrict__ fcw,
                                                     float* __restrict__ out) {
    __shared__ __align__(16) unsigned short dbuf[DN * EDIM];  // 64 KB
    __shared__ __align__(16) unsigned short qbuf[QN * EDIM];  // 8 KB; overlaid by part[8][16][NK]
    __shared__ float redS[8];

    // chain literals: Cj = inv_sqrt_2pi * e^{-4*T(j)}, T = 0,4,12,24,40 cumulative
    const float C0 = 0.3989422804014327f;
    const float C1 = 7.30620157e-3f;
    const float C2 = 2.45119242e-6f;
    const float C3 = 1.50605972e-11f;
    const float C4 = 1.69484929e-18f;

    int b = blockIdx.x, tid = threadIdx.x;
    int w = tid >> 6, lane = tid & 63;
    int lr = lane & 15, lg = lane >> 4;
    int qt = w & 1, ds = w >> 1;

    const int* qtb = qtok + b * QN;
    const int* dtb = dtok + b * DN;

    // ---- issue ALL token loads up front ----
    int tq = qtb[(w << 2) + lg];                       // q row this thread stages
    int tdA[4], tdB[4];
    #pragma unroll
    for (int it = 0; it < 4; ++it) {
        tdA[it] = dtb[(w << 4) + (it << 2) + lg];
        tdB[it] = dtb[128 + (w << 4) + (it << 2) + lg];
    }
    int tcurs[4], qtr[4];
    #pragma unroll
    for (int t = 0; t < 4; ++t) tcurs[t] = dtb[(t << 6) + (ds << 4) + lr];
    #pragma unroll
    for (int r = 0; r < 4; ++r) qtr[r] = qtb[(qt << 4) + (lg << 2) + r];

    // ---- issue all 18 row loads (9 rows x 32B/lane) ----
    const float4* qsrc = (const float4*)(emb + (size_t)tq * EDIM) + lr * 2;
    float4 qv0 = qsrc[0], qv1 = qsrc[1];
    float4 av[4][2], bv[4][2];
    #pragma unroll
    for (int it = 0; it < 4; ++it) {
        const float4* s0 = (const float4*)(emb + (size_t)tdA[it] * EDIM) + lr * 2;
        av[it][0] = s0[0]; av[it][1] = s0[1];
    }
    #pragma unroll
    for (int it = 0; it < 4; ++it) {
        const float4* s1 = (const float4*)(emb + (size_t)tdB[it] * EDIM) + lr * 2;
        bv[it][0] = s1[0]; bv[it][1] = s1[1];
    }

    // ---- process q row: normalize, pack, swizzled LDS ----
    {
        int qr = (w << 2) + lg;
        float inv = 1.0f / sqrtf(sum16(sumsq8(qv0, qv1)));
        qv0.x *= inv; qv0.y *= inv; qv0.z *= inv; qv0.w *= inv;
        qv1.x *= inv; qv1.y *= inv; qv1.z *= inv; qv1.w *= inv;
        *(bf16x8*)((char*)qbuf + qr * 256 + swz(qr, lr * 16)) = pack8(qv0, qv1);
    }
    // ---- process 8 d rows ----
    #pragma unroll
    for (int it = 0; it < 4; ++it) {
        int r = (w << 4) + (it << 2) + lg;
        float inv = 1.0f / sqrtf(sum16(sumsq8(av[it][0], av[it][1])));
        float4 v0 = av[it][0], v1 = av[it][1];
        v0.x *= inv; v0.y *= inv; v0.z *= inv; v0.w *= inv;
        v1.x *= inv; v1.y *= inv; v1.z *= inv; v1.w *= inv;
        *(bf16x8*)((char*)dbuf + r * 256 + swz(r, lr * 16)) = pack8(v0, v1);
    }
    #pragma unroll
    for (int it = 0; it < 4; ++it) {
        int r = 128 + (w << 4) + (it << 2) + lg;
        float inv = 1.0f / sqrtf(sum16(sumsq8(bv[it][0], bv[it][1])));
        float4 v0 = bv[it][0], v1 = bv[it][1];
        v0.x *= inv; v0.y *= inv; v0.z *= inv; v0.w *= inv;
        v1.x *= inv; v1.y *= inv; v1.z *= inv; v1.w *= inv;
        *(bf16x8*)((char*)dbuf + r * 256 + swz(r, lr * 16)) = pack8(v0, v1);
    }
    __syncthreads();                                  // bar1: all LDS staged

    // ---- A fragments ----
    bf16x8 A0, A1, A2, A3;
    {
        int qr = (qt << 4) + lr;
        const char* qb = (const char*)qbuf + qr * 256;
        A0 = *(const bf16x8*)(qb + swz(qr, lg * 16));
        A1 = *(const bf16x8*)(qb + swz(qr, lg * 16 + 64));
        A2 = *(const bf16x8*)(qb + swz(qr, lg * 16 + 128));
        A3 = *(const bf16x8*)(qb + swz(qr, lg * 16 + 192));
    }

    float kacc[4][NK];
    #pragma unroll
    for (int r = 0; r < 4; ++r)
        #pragma unroll
        for (int k = 0; k < NK; ++k) kacc[r][k] = 0.0f;

    #pragma unroll
    for (int t = 0; t < 4; ++t) {
        int dr = (t << 6) + (ds << 4) + lr;
        const char* db = (const char*)dbuf + dr * 256;
        bf16x8 B0 = *(const bf16x8*)(db + swz(dr, lg * 16));
        bf16x8 B1 = *(const bf16x8*)(db + swz(dr, lg * 16 + 64));
        bf16x8 B2 = *(const bf16x8*)(db + swz(dr, lg * 16 + 128));
        bf16x8 B3 = *(const bf16x8*)(db + swz(dr, lg * 16 + 192));
        int tcur = tcurs[t];

        f32x4 acc = {0.0f, 0.0f, 0.0f, 0.0f};
        acc = __builtin_amdgcn_mfma_f32_16x16x32_bf16(A0, B0, acc, 0, 0, 0);
        acc = __builtin_amdgcn_mfma_f32_16x16x32_bf16(A1, B1, acc, 0, 0, 0);
        acc = __builtin_amdgcn_mfma_f32_16x16x32_bf16(A2, B2, acc, 0, 0, 0);
        acc = __builtin_amdgcn_mfma_f32_16x16x32_bf16(A3, B3, acc, 0, 0, 0);

        bool dok = (tcur > 0);
        float mc = dok ? C0 : 0.0f;
        #pragma unroll
        for (int r = 0; r < 4; ++r) {
            float t2 = acc[r];                            // rows pre-normalized
            kacc[r][0] += (tcur == qtr[r]) ? mc : 0.0f;   // K0: exact token match
            float d  = t2 - 0.1f;
            float g  = EXP2F(d * d * -72.1347520f);       // exp(-50(t-0.1)^2) = K5 shape
            g = dok ? g : 0.0f;
            float Em = EXP2F(t2 * -28.8539008f);          // e^{-20t}
            float Ep = EXP2F(t2 *  28.8539008f);          // e^{+20t}
            float h = g;
            kacc[r][5]  += h * C0;
            h *= Em; kacc[r][6]  += h * C0;
            h *= Em; kacc[r][7]  += h * C1;
            h *= Em; kacc[r][8]  += h * C2;
            h *= Em; kacc[r][9]  += h * C3;
            h *= Em; kacc[r][10] += h * C4;
            h = g;
            h *= Ep; kacc[r][4]  += h * C1;
            h *= Ep; kacc[r][3]  += h * C2;
            h *= Ep; kacc[r][2]  += h * C3;
            h *= Ep; kacc[r][1]  += h * C4;
        }
    }

    // ---- DPP reduce over 16 doc-columns; overlay partials on qbuf ----
    __syncthreads();                                  // bar2: all qbuf A-reads done
    float* part = (float*)qbuf;
    #pragma unroll
    for (int r = 0; r < 4; ++r)
        #pragma unroll
        for (int k = 0; k < NK; ++k) kacc[r][k] = sum16(kacc[r][k]);
    if (lr == 0) {
        float* pw = part + w * (16 * NK) + (lg << 2) * NK;
        #pragma unroll
        for (int r = 0; r < 4; ++r)
            #pragma unroll
            for (int k = 0; k < NK; ++k)
                pw[r * NK + k] = kacc[r][k];
    }
    __syncthreads();                                  // bar3: partials visible

    // ---- combine 4 dspans, log-pool, weighted sum -> out[b] ----
    float total = 0.0f;
    if (tid < QN * NK) {
        int q = tid / NK, k = tid - (tid / NK) * NK;
        int qt2 = q >> 4, row = q & 15;
        const float* pb = part + qt2 * (16 * NK) + row * NK + k;
        float v = pb[0] + pb[2 * 16 * NK] + pb[4 * 16 * NK] + pb[6 * 16 * NK];
        float m = (qtb[q] > 0) ? 1.0f : 0.0f;
        total = m * fcw[k] * __logf(fmaxf(v, 1e-10f));
    }
    #pragma unroll
    for (int off = 32; off; off >>= 1) total += __shfl_xor(total, off);
    if (lane == 0) redS[w] = total;
    __syncthreads();                                  // bar4
    if (tid == 0) {
        float s = 0.0f;
        #pragma unroll
        for (int i = 0; i < 8; ++i) s += redS[i];
        out[b] = s;
    }
}

extern "C" void kernel_launch(void* const* d_in, const int* in_sizes, int n_in,
                              void* d_out, int out_size, void* d_ws, size_t ws_size,
                              hipStream_t stream) {
    const int*   qtok = (const int*)d_in[0];
    const int*   dtok = (const int*)d_in[1];
    const float* emb  = (const float*)d_in[2];
    const float* fcw  = (const float*)d_in[3];
    float* out = (float*)d_out;

    int B = in_sizes[0] / QN;                  // 512
    knrm_fused<<<B, 512, 0, stream>>>(qtok, dtok, emb, fcw, out);
}